// Round 6
// baseline (117.971 us; speedup 1.0000x reference)
//
#include <hip/hip_runtime.h>
#include <cstdint>
#include <cstddef>

#define LOG2E 1.4426950408889634f

typedef float f4v __attribute__((ext_vector_type(4)));

// ---- DPP cross-lane add: v += v[permuted lane] (pure VALU, no LDS pipe) ----
template<int CTRL>
__device__ __forceinline__ float dpp_addf(float v) {
  const int s = __builtin_amdgcn_update_dpp(
      0, __builtin_bit_cast(int, v), CTRL, 0xF, 0xF, true);
  return v + __builtin_bit_cast(float, s);
}
#define DPP_XOR1     0xB1   // quad_perm [1,0,3,2]
#define DPP_XOR2     0x4E   // quad_perm [2,3,0,1]
#define DPP_HALF_MIR 0x141  // 8-lane mirror (completes 8-group after XOR1,2)
#define DPP_ROW_MIR  0x140  // 16-lane mirror (completes 16-group)

// async global->LDS: HW writes wave-uniform LDS base + lane*16B (vmcnt)
__device__ __forceinline__ void gld_lds16(const float* g, float* l) {
  __builtin_amdgcn_global_load_lds(
      (const __attribute__((address_space(1))) void*)g,
      (__attribute__((address_space(3))) void*)l, 16, 0, 0);
}

// involution swizzle on 16B-block index: frag reads land 8 lanes/bank-quad
__device__ __forceinline__ int swz(int b) { return b ^ ((b >> 3) & 7); }

// stage one 16KB half (512 rows x 8 k), 8-wave block: LDS[blk]=G[swz(blk)]
__device__ __forceinline__ void stage_half(const float* Wg, float* buf,
                                           int wv, int ln) {
  #pragma unroll
  for (int t = 0; t < 2; ++t) {
    const int seg = ((wv << 1) + t) << 8;      // wave-uniform dest word base
    const int j   = swz((seg >> 2) + ln);      // source 16B-block for this slot
    gld_lds16(Wg + ((j >> 1) << 4) + ((j & 1) << 2), buf + seg);
  }
}

// full 32KB W tile for one i: k 0..7 -> buf[0..4095], k 8..15 -> buf[4096..]
__device__ __forceinline__ void stage_tile(const float* WtI, float* buf,
                                           int wv, int ln) {
  stage_half(WtI,     buf,        wv, ln);
  stage_half(WtI + 8, buf + 4096, wv, ln);
}

// barrier waiting LDS ops only; async W staging (vmcnt) stays in flight (T4)
__device__ __forceinline__ void lds_barrier() {
  asm volatile("s_waitcnt lgkmcnt(0)\n\ts_barrier" ::: "memory");
}

// Launder a wave-uniform pointer into SGPRs (readfirstlane both halves) so
// "s" asm constraints are satisfiable. bh=tid>>8 is uniform per 64-lane wave
// but the compiler can't prove it.
__device__ __forceinline__ const float* uniform_fptr(const float* p) {
  const uint64_t u = (uint64_t)p;
  const uint32_t lo = __builtin_amdgcn_readfirstlane((uint32_t)u);
  const uint32_t hi = __builtin_amdgcn_readfirstlane((uint32_t)(u >> 32));
  return (const float*)(((uint64_t)hi << 32) | lo);
}

// x[b][0..15], x[b+1][0..15] -> SGPRs via scalar loads (uniform addresses).
// Loads + wait fused in ONE asm: consumers data-depend on outputs.
__device__ __forceinline__ void sload_x2(const float* p0, const float* p1,
                                         f4v& a0, f4v& a1, f4v& a2, f4v& a3,
                                         f4v& b0, f4v& b1, f4v& b2, f4v& b3) {
  asm volatile(
      "s_load_dwordx4 %0, %8, 0\n\t"
      "s_load_dwordx4 %1, %8, 16\n\t"
      "s_load_dwordx4 %2, %8, 32\n\t"
      "s_load_dwordx4 %3, %8, 48\n\t"
      "s_load_dwordx4 %4, %9, 0\n\t"
      "s_load_dwordx4 %5, %9, 16\n\t"
      "s_load_dwordx4 %6, %9, 32\n\t"
      "s_load_dwordx4 %7, %9, 48\n\t"
      "s_waitcnt lgkmcnt(0)"
      : "=&s"(a0), "=&s"(a1), "=&s"(a2), "=&s"(a3),
        "=&s"(b0), "=&s"(b1), "=&s"(b2), "=&s"(b3)
      : "s"(p0), "s"(p1));
}

// K1: grid 512 (bg=1: W read once), block 512 thr (8 waves), 4 i's x all 32 b.
// Ring-2 full-tile double buffer: ONE vmcnt(0) drain per iteration (loop-top
// __syncthreads), with a full iteration of prefetch distance; the two
// mid-iteration producer/consumer barriers are lgkmcnt-only so the next-tile
// W prefetch stays in flight across them.
//
// NO __launch_bounds__ second arg. Experiment matrix rounds 1-5: every
// variant declaring a min-occupancy hint (512,4)/(512,2) pegged VGPR at the
// derived cap (64/128) and emitted 165MB-1.3GB of scratch traffic, across
// THREE different scheduling structures; the baseline with plain (512)
// allocated 72 VGPR with zero scratch. The hint flips the pre-RA scheduler
// into budget-filling mode and its pressure overshoot spills. Occupancy
// doesn't need the hint: LDS=71KB already caps at 2 blocks/CU.
template<bool ATOMIC>
__global__ __launch_bounds__(512)
void caps_main(const float* __restrict__ X, const float* __restrict__ Wt,
               float* __restrict__ part) {
  __shared__ float sW[2][8192];     // 64 KB: double-buffered full W tiles
  __shared__ float sWs[32 * 20];    // d-summed W (2.5 KB)
  __shared__ float sC[32 * 36];     // c2[n][b] (4.5 KB)
  // total 71 KB -> 2 blocks/CU

  const int tid  = threadIdx.x;
  const int wv   = tid >> 6, ln = tid & 63;
  const int t256 = tid & 255;
  const int bh   = tid >> 8;                  // b-half for pass 2
  const int i0   = blockIdx.x << 2;

  stage_tile(Wt + ((size_t)i0 << 13), sW[0], wv, ln);

  const int bB = tid >> 4;                    // phase-B batch 0..31
  const int n1 = tid & 15;                    // phase-B n-low
  const int j0 = t256 << 2;                   // lane's base 16B-block
  const int nr = t256 >> 3;                   // lane's capsule (both rows)

  float acc0[16], acc1[16];
  #pragma unroll
  for (int b = 0; b < 16; ++b) { acc0[b] = 0.f; acc1[b] = 0.f; }

  #pragma unroll
  for (int ii = 0; ii < 4; ++ii) {
    const int p = ii & 1;                     // static after unroll
    __syncthreads();                          // W(ii) staged (full-iter-old)

    // phase-B x loaded early (before next-tile staging -> older in the vmcnt
    // scoreboard -> phase B's wait is counted, not a drain)
    const float* xg = X + ((size_t)bB << 15) + ((size_t)(i0 + ii) << 4);
    const float4 x0 = *(const float4*)(xg + 0);
    const float4 x1 = *(const float4*)(xg + 4);
    const float4 x2 = *(const float4*)(xg + 8);
    const float4 x3 = *(const float4*)(xg + 12);

    if (ii < 3)                               // prefetch next i: full-iter dist
      stage_tile(Wt + ((size_t)(i0 + ii + 1) << 13), sW[p ^ 1], wv, ln);

    // ---- phase A: lane rows -> regs (static buffer index => BasicAA keeps
    // these ds_reads un-ordered vs the async stage into buf p^1) ----
    const float* sWp = &sW[p][0];
    const float4 wa0 = *(const float4*)&sWp[swz(j0 + 0) << 2];
    const float4 wa1 = *(const float4*)&sWp[swz(j0 + 1) << 2];
    const float4 wb0 = *(const float4*)&sWp[swz(j0 + 2) << 2];
    const float4 wb1 = *(const float4*)&sWp[swz(j0 + 3) << 2];
    const float4 wa2 = *(const float4*)&sWp[4096 + (swz(j0 + 0) << 2)];
    const float4 wa3 = *(const float4*)&sWp[4096 + (swz(j0 + 1) << 2)];
    const float4 wb2 = *(const float4*)&sWp[4096 + (swz(j0 + 2) << 2)];
    const float4 wb3 = *(const float4*)&sWp[4096 + (swz(j0 + 3) << 2)];

    // ---- Ws[n][k] from frags via DPP 8-lane reduce (waves 0-3 cover all n) ----
    if (tid < 256) {
      float pr[16] = { wa0.x+wb0.x, wa0.y+wb0.y, wa0.z+wb0.z, wa0.w+wb0.w,
                       wa1.x+wb1.x, wa1.y+wb1.y, wa1.z+wb1.z, wa1.w+wb1.w,
                       wa2.x+wb2.x, wa2.y+wb2.y, wa2.z+wb2.z, wa2.w+wb2.w,
                       wa3.x+wb3.x, wa3.y+wb3.y, wa3.z+wb3.z, wa3.w+wb3.w };
      #pragma unroll
      for (int q = 0; q < 16; ++q) {
        float v = pr[q];
        v = dpp_addf<DPP_XOR1>(v);
        v = dpp_addf<DPP_XOR2>(v);
        v = dpp_addf<DPP_HALF_MIR>(v);
        pr[q] = v;
      }
      if ((tid & 7) < 4) {
        const int m = tid & 3;
        const float4 w =
            (m & 2) ? ((m & 1) ? make_float4(pr[12], pr[13], pr[14], pr[15])
                               : make_float4(pr[8],  pr[9],  pr[10], pr[11]))
                    : ((m & 1) ? make_float4(pr[4],  pr[5],  pr[6],  pr[7])
                               : make_float4(pr[0],  pr[1],  pr[2],  pr[3]));
        *(float4*)&sWs[(t256 >> 3) * 20 + (m << 2)] = w;
      }
    }
    lds_barrier();                            // sWs ready (vmcnt untouched)

    // ---- phase B: x (regs) -> 2-round softmax -> sC ----
    {
      float t1 = 0.f, t2 = 0.f;
      #pragma unroll
      for (int c4 = 0; c4 < 4; ++c4) {
        const float4 A1 = *(const float4*)&sWs[n1 * 20 + (c4 << 2)];
        const float4 A2 = *(const float4*)&sWs[(n1 + 16) * 20 + (c4 << 2)];
        const float4 xc = (c4 == 0) ? x0 : (c4 == 1) ? x1 : (c4 == 2) ? x2 : x3;
        t1 += A1.x * xc.x + A1.y * xc.y + A1.z * xc.z + A1.w * xc.w;
        t2 += A2.x * xc.x + A2.y * xc.y + A2.z * xc.z + A2.w * xc.w;
      }
      const float l1a = t1 * 0.03125f, l1b = t2 * 0.03125f;   // b1 = t/32
      const float e1a = exp2f(l1a * LOG2E), e1b = exp2f(l1b * LOG2E);
      float s1 = e1a + e1b;
      s1 = dpp_addf<DPP_XOR1>(s1); s1 = dpp_addf<DPP_XOR2>(s1);
      s1 = dpp_addf<DPP_HALF_MIR>(s1); s1 = dpp_addf<DPP_ROW_MIR>(s1);
      const float rs1 = __builtin_amdgcn_rcpf(s1);
      const float l2a = l1a + e1a * rs1 * t1;                 // b2 = b1 + c1*t
      const float l2b = l1b + e1b * rs1 * t2;
      const float e2a = exp2f(l2a * LOG2E), e2b = exp2f(l2b * LOG2E);
      float s2 = e2a + e2b;
      s2 = dpp_addf<DPP_XOR1>(s2); s2 = dpp_addf<DPP_XOR2>(s2);
      s2 = dpp_addf<DPP_HALF_MIR>(s2); s2 = dpp_addf<DPP_ROW_MIR>(s2);
      const float rs2 = __builtin_amdgcn_rcpf(s2);
      sC[n1 * 36 + bB]        = e2a * rs2;
      sC[(n1 + 16) * 36 + bB] = e2b * rs2;
    }
    lds_barrier();                            // sC ready (vmcnt untouched)

    // ---- pass 2: x in SGPRs (s_load), FMAs v*s -> acc ----
    float c2s[16];
    {
      const int cb = nr * 36 + (bh << 4);
      *(float4*)&c2s[0]  = *(const float4*)&sC[cb + 0];
      *(float4*)&c2s[4]  = *(const float4*)&sC[cb + 4];
      *(float4*)&c2s[8]  = *(const float4*)&sC[cb + 8];
      *(float4*)&c2s[12] = *(const float4*)&sC[cb + 12];
    }
    const size_t xoff = ((size_t)(i0 + ii) << 4);
    const float* pbase = uniform_fptr(X + (((size_t)(bh << 4)) << 15) + xoff);
    #pragma unroll
    for (int cl = 0; cl < 8; ++cl) {
      const float* p0 = pbase + ((size_t)(cl << 1) << 15);  // SGPR arithmetic
      const float* p1 = p0 + 32768;
      f4v xa0, xa1, xa2, xa3, xb0, xb1, xb2, xb3;
      sload_x2(p0, p1, xa0, xa1, xa2, xa3, xb0, xb1, xb2, xb3);
      float u0 = wa0.x*xa0.x + wa0.y*xa0.y + wa0.z*xa0.z + wa0.w*xa0.w
               + wa1.x*xa1.x + wa1.y*xa1.y + wa1.z*xa1.z + wa1.w*xa1.w
               + wa2.x*xa2.x + wa2.y*xa2.y + wa2.z*xa2.z + wa2.w*xa2.w
               + wa3.x*xa3.x + wa3.y*xa3.y + wa3.z*xa3.z + wa3.w*xa3.w;
      float u1 = wb0.x*xa0.x + wb0.y*xa0.y + wb0.z*xa0.z + wb0.w*xa0.w
               + wb1.x*xa1.x + wb1.y*xa1.y + wb1.z*xa1.z + wb1.w*xa1.w
               + wb2.x*xa2.x + wb2.y*xa2.y + wb2.z*xa2.z + wb2.w*xa2.w
               + wb3.x*xa3.x + wb3.y*xa3.y + wb3.z*xa3.z + wb3.w*xa3.w;
      float v0 = wa0.x*xb0.x + wa0.y*xb0.y + wa0.z*xb0.z + wa0.w*xb0.w
               + wa1.x*xb1.x + wa1.y*xb1.y + wa1.z*xb1.z + wa1.w*xb1.w
               + wa2.x*xb2.x + wa2.y*xb2.y + wa2.z*xb2.z + wa2.w*xb2.w
               + wa3.x*xb3.x + wa3.y*xb3.y + wa3.z*xb3.z + wa3.w*xb3.w;
      float v1 = wb0.x*xb0.x + wb0.y*xb0.y + wb0.z*xb0.z + wb0.w*xb0.w
               + wb1.x*xb1.x + wb1.y*xb1.y + wb1.z*xb1.z + wb1.w*xb1.w
               + wb2.x*xb2.x + wb2.y*xb2.y + wb2.z*xb2.z + wb2.w*xb2.w
               + wb3.x*xb3.x + wb3.y*xb3.y + wb3.z*xb3.z + wb3.w*xb3.w;
      acc0[(cl << 1)    ] += c2s[(cl << 1)    ] * u0;
      acc1[(cl << 1)    ] += c2s[(cl << 1)    ] * u1;
      acc0[(cl << 1) + 1] += c2s[(cl << 1) + 1] * v0;
      acc1[(cl << 1) + 1] += c2s[(cl << 1) + 1] * v1;
    }
  }

  if constexpr (ATOMIC) {
    #pragma unroll
    for (int j = 0; j < 16; ++j) {
      const int bgl = (bh << 4) + j;
      float* dst = part + ((size_t)bgl << 9) + (t256 << 1);
      atomicAdd(dst, acc0[j]);
      atomicAdd(dst + 1, acc1[j]);
    }
  } else {
    float* wp = part + ((size_t)blockIdx.x << 14) + (t256 << 1);
    #pragma unroll
    for (int j = 0; j < 16; ++j) {
      const int bgl = (bh << 4) + j;
      *(float2*)(wp + ((size_t)bgl << 9)) = make_float2(acc0[j], acc1[j]);
    }
  }
}

// K2: reduce 512 partials + squash. grid 256 (b = bid>>3, r-block = bid&7).
__global__ __launch_bounds__(512)
void caps_reduce(const float* __restrict__ part, float* __restrict__ out) {
  __shared__ float sred[32][64];
  const int tid = threadIdx.x;
  const int bid = blockIdx.x;            // 0..255
  const int b  = bid >> 3;               // 0..31
  const int rb = bid & 7;                // 64-elem row block
  const int pg = tid >> 4;               // 0..31: sums ig in [16pg, 16pg+16)
  const int sl = tid & 15;               // float4 slot
  const float* src = part + (((size_t)pg << 4) << 14)
                   + (b << 9) + (rb << 6) + (sl << 2);
  float4 a = make_float4(0.f, 0.f, 0.f, 0.f);
  #pragma unroll 4
  for (int p = 0; p < 16; ++p) {
    const float4 v = *(const float4*)(src + ((size_t)p << 14));
    a.x += v.x; a.y += v.y; a.z += v.z; a.w += v.w;
  }
  *(float4*)&sred[pg][sl << 2] = a;
  __syncthreads();
  if (tid < 64) {
    float s = 0.f;
    #pragma unroll
    for (int g = 0; g < 32; ++g) s += sred[g][tid];
    float sq = s * s;
    sq += __shfl_xor(sq, 1); sq += __shfl_xor(sq, 2);
    sq += __shfl_xor(sq, 4); sq += __shfl_xor(sq, 8);   // sum over d (16 r's)
    const float scale = sq / (1.0f + sq) / sqrtf(sq + 1e-7f);
    out[(b << 9) + (rb << 6) + tid] = scale * s;
  }
}

// fallback path: squash fully-accumulated sums
__global__ __launch_bounds__(256)
void caps_squash(const float* __restrict__ sums, float* __restrict__ out) {
  const int e = (blockIdx.x << 8) + threadIdx.x;
  const float s = sums[e];
  float sq = s * s;
  sq += __shfl_xor(sq, 1); sq += __shfl_xor(sq, 2);
  sq += __shfl_xor(sq, 4); sq += __shfl_xor(sq, 8);
  const float scale = sq / (1.0f + sq) / sqrtf(sq + 1e-7f);
  out[e] = scale * s;
}

extern "C" void kernel_launch(void* const* d_in, const int* in_sizes, int n_in,
                              void* d_out, int out_size, void* d_ws, size_t ws_size,
                              hipStream_t stream) {
  const float* X  = (const float*)d_in[0];
  const float* Wt = (const float*)d_in[1];
  float* out = (float*)d_out;
  float* wsf = (float*)d_ws;
  const size_t need = (size_t)512 * 16384 * sizeof(float);
  if (ws_size >= need) {
    caps_main<false><<<512, 512, 0, stream>>>(X, Wt, wsf);
    caps_reduce<<<256, 512, 0, stream>>>(wsf, out);
  } else {
    float* acc = (ws_size >= (size_t)16384 * sizeof(float)) ? wsf : out;
    hipMemsetAsync(acc, 0, 16384 * sizeof(float), stream);
    caps_main<true><<<512, 512, 0, stream>>>(X, Wt, acc);
    caps_squash<<<64, 256, 0, stream>>>(acc, out);
  }
}

// Round 7
// 45.798 us; speedup vs baseline: 2.5759x; 2.5759x over previous
//
#include <hip/hip_runtime.h>
#include <cstdint>
#include <cstddef>

#define LOG2E 1.4426950408889634f

typedef float f4v __attribute__((ext_vector_type(4)));

// ---- DPP cross-lane add: v += v[permuted lane] (pure VALU, no LDS pipe) ----
template<int CTRL>
__device__ __forceinline__ float dpp_addf(float v) {
  const int s = __builtin_amdgcn_update_dpp(
      0, __builtin_bit_cast(int, v), CTRL, 0xF, 0xF, true);
  return v + __builtin_bit_cast(float, s);
}
#define DPP_XOR1     0xB1   // quad_perm [1,0,3,2]
#define DPP_XOR2     0x4E   // quad_perm [2,3,0,1]
#define DPP_HALF_MIR 0x141  // 8-lane mirror (completes 8-group after XOR1,2)
#define DPP_ROW_MIR  0x140  // 16-lane mirror (completes 16-group)

// async global->LDS: HW writes wave-uniform LDS base + lane*16B (vmcnt)
__device__ __forceinline__ void gld_lds16(const float* g, float* l) {
  __builtin_amdgcn_global_load_lds(
      (const __attribute__((address_space(1))) void*)g,
      (__attribute__((address_space(3))) void*)l, 16, 0, 0);
}

// involution swizzle on 16B-block index: frag reads land 8 lanes/bank-quad
__device__ __forceinline__ int swz(int b) { return b ^ ((b >> 3) & 7); }

// stage one 16KB half (512 rows x 8 k), 8-wave block: LDS[blk]=G[swz(blk)]
__device__ __forceinline__ void stage_half(const float* Wg, float* buf,
                                           int wv, int ln) {
  #pragma unroll
  for (int t = 0; t < 2; ++t) {
    const int seg = ((wv << 1) + t) << 8;      // wave-uniform dest word base
    const int j   = swz((seg >> 2) + ln);      // source 16B-block for this slot
    gld_lds16(Wg + ((j >> 1) << 4) + ((j & 1) << 2), buf + seg);
  }
}

// full 32KB W tile for one i: k 0..7 -> buf[0..4095], k 8..15 -> buf[4096..]
__device__ __forceinline__ void stage_tile(const float* WtI, float* buf,
                                           int wv, int ln) {
  stage_half(WtI,     buf,        wv, ln);
  stage_half(WtI + 8, buf + 4096, wv, ln);
}

// barrier waiting LDS ops only; async W staging (vmcnt) stays in flight (T4)
__device__ __forceinline__ void lds_barrier() {
  asm volatile("s_waitcnt lgkmcnt(0)\n\ts_barrier" ::: "memory");
}

// Launder a wave-uniform pointer into SGPRs (readfirstlane both halves) so
// "s" asm constraints are satisfiable. bh=tid>>8 is uniform per 64-lane wave
// but the compiler can't prove it.
__device__ __forceinline__ const float* uniform_fptr(const float* p) {
  const uint64_t u = (uint64_t)p;
  const uint32_t lo = __builtin_amdgcn_readfirstlane((uint32_t)u);
  const uint32_t hi = __builtin_amdgcn_readfirstlane((uint32_t)(u >> 32));
  return (const float*)(((uint64_t)hi << 32) | lo);
}

// x[b][0..15], x[b+1][0..15] -> SGPRs via scalar loads (uniform addresses).
// Loads + wait fused in ONE asm: consumers data-depend on outputs.
__device__ __forceinline__ void sload_x2(const float* p0, const float* p1,
                                         f4v& a0, f4v& a1, f4v& a2, f4v& a3,
                                         f4v& b0, f4v& b1, f4v& b2, f4v& b3) {
  asm volatile(
      "s_load_dwordx4 %0, %8, 0\n\t"
      "s_load_dwordx4 %1, %8, 16\n\t"
      "s_load_dwordx4 %2, %8, 32\n\t"
      "s_load_dwordx4 %3, %8, 48\n\t"
      "s_load_dwordx4 %4, %9, 0\n\t"
      "s_load_dwordx4 %5, %9, 16\n\t"
      "s_load_dwordx4 %6, %9, 32\n\t"
      "s_load_dwordx4 %7, %9, 48\n\t"
      "s_waitcnt lgkmcnt(0)"
      : "=&s"(a0), "=&s"(a1), "=&s"(a2), "=&s"(a3),
        "=&s"(b0), "=&s"(b1), "=&s"(b2), "=&s"(b3)
      : "s"(p0), "s"(p1));
}

// K1: grid 512 (bg=1: W read once), block 512 thr (8 waves), 4 i's x all 32 b.
//
// SINGLE-buffer deep prefetch, ROLLED loop. Post-mortem of rounds 1-6: every
// spilling variant required compile-time buffer parity (p=ii&1) and thus a
// full 4x unroll; 4 bodies (96+ live values each) in one scheduler scope
// stretched live ranges past 128 VGPRs -> 165MB-1.3GB scratch, independent
// of barrier type / x placement / launch bounds. The baseline's 72-VGPR
// allocation comes from its ROLLED loop. Single-buffering removes the parity
// variable entirely: after an lgkm-only barrier confirms all waves' frag
// reads, the SAME sW can take the next tile's async staging (nothing reads
// sW again until the next loop-top __syncthreads, which drains vmcnt with a
// full iteration of prefetch distance). vs baseline: the zero-distance
// mid-iteration vmcnt drain (2nd __syncthreads waiting on h1 staged ~20
// instructions earlier) is gone; same barrier count (1 sync + 3 lds).
template<bool ATOMIC>
__global__ __launch_bounds__(512)
void caps_main(const float* __restrict__ X, const float* __restrict__ Wt,
               float* __restrict__ part) {
  __shared__ float sW[8192];        // 32 KB: single W tile (deep prefetch)
  __shared__ float sWs[32 * 20];    // d-summed W (2.5 KB)
  __shared__ float sC[32 * 36];     // c2[n][b] (4.5 KB)
  __shared__ float sPad[3968];      // occupancy shaper: total 54.5KB -> 2 blk/CU
  if ((int)blockIdx.x == -1) sPad[threadIdx.x] = 1.f;   // keep sPad allocated

  const int tid  = threadIdx.x;
  const int wv   = tid >> 6, ln = tid & 63;
  const int t256 = tid & 255;
  const int bh   = tid >> 8;                  // b-half for pass 2
  const int i0   = blockIdx.x << 2;

  stage_tile(Wt + ((size_t)i0 << 13), sW, wv, ln);

  const int bB = tid >> 4;                    // phase-B batch 0..31
  const int n1 = tid & 15;                    // phase-B n-low
  const int j0 = t256 << 2;                   // lane's base 16B-block
  const int nr = t256 >> 3;                   // lane's capsule (both rows)

  float acc0[16], acc1[16];
  #pragma unroll
  for (int b = 0; b < 16; ++b) { acc0[b] = 0.f; acc1[b] = 0.f; }

  #pragma clang loop unroll(disable)
  for (int ii = 0; ii < 4; ++ii) {
    __syncthreads();                // vmcnt drain: tile(ii) staged full iter ago

    // phase-B x loaded early: oldest vmem -> phase B's wait is counted,
    // leaving the next tile's staging in flight
    const float* xg = X + ((size_t)bB << 15) + ((size_t)(i0 + ii) << 4);
    const float4 x0 = *(const float4*)(xg + 0);
    const float4 x1 = *(const float4*)(xg + 4);
    const float4 x2 = *(const float4*)(xg + 8);
    const float4 x3 = *(const float4*)(xg + 12);

    // ---- phase A: all 8 lane rows -> regs (tile ii) ----
    const float4 wa0 = *(const float4*)&sW[swz(j0 + 0) << 2];
    const float4 wa1 = *(const float4*)&sW[swz(j0 + 1) << 2];
    const float4 wb0 = *(const float4*)&sW[swz(j0 + 2) << 2];
    const float4 wb1 = *(const float4*)&sW[swz(j0 + 3) << 2];
    const float4 wa2 = *(const float4*)&sW[4096 + (swz(j0 + 0) << 2)];
    const float4 wa3 = *(const float4*)&sW[4096 + (swz(j0 + 1) << 2)];
    const float4 wb2 = *(const float4*)&sW[4096 + (swz(j0 + 2) << 2)];
    const float4 wb3 = *(const float4*)&sW[4096 + (swz(j0 + 3) << 2)];

    lds_barrier();                  // all waves' frag reads done; sW now free
                                    // (lgkm-only: vmcnt stays in flight)

    if (ii < 3)                     // stage tile(ii+1) into the SAME buffer;
      stage_tile(Wt + ((size_t)(i0 + ii + 1) << 13), sW, wv, ln);
                                    // async; drained at next loop-top sync

    // ---- Ws[n][k] from frags via DPP 8-lane reduce (waves 0-3 cover all n) ----
    if (tid < 256) {
      float pr[16] = { wa0.x+wb0.x, wa0.y+wb0.y, wa0.z+wb0.z, wa0.w+wb0.w,
                       wa1.x+wb1.x, wa1.y+wb1.y, wa1.z+wb1.z, wa1.w+wb1.w,
                       wa2.x+wb2.x, wa2.y+wb2.y, wa2.z+wb2.z, wa2.w+wb2.w,
                       wa3.x+wb3.x, wa3.y+wb3.y, wa3.z+wb3.z, wa3.w+wb3.w };
      #pragma unroll
      for (int q = 0; q < 16; ++q) {
        float v = pr[q];
        v = dpp_addf<DPP_XOR1>(v);
        v = dpp_addf<DPP_XOR2>(v);
        v = dpp_addf<DPP_HALF_MIR>(v);
        pr[q] = v;
      }
      if ((tid & 7) < 4) {
        const int m = tid & 3;
        const float4 w =
            (m & 2) ? ((m & 1) ? make_float4(pr[12], pr[13], pr[14], pr[15])
                               : make_float4(pr[8],  pr[9],  pr[10], pr[11]))
                    : ((m & 1) ? make_float4(pr[4],  pr[5],  pr[6],  pr[7])
                               : make_float4(pr[0],  pr[1],  pr[2],  pr[3]));
        *(float4*)&sWs[(t256 >> 3) * 20 + (m << 2)] = w;
      }
    }
    lds_barrier();                            // sWs ready (vmcnt untouched)

    // ---- phase B: x (regs) -> 2-round softmax -> sC ----
    {
      float t1 = 0.f, t2 = 0.f;
      #pragma unroll
      for (int c4 = 0; c4 < 4; ++c4) {
        const float4 A1 = *(const float4*)&sWs[n1 * 20 + (c4 << 2)];
        const float4 A2 = *(const float4*)&sWs[(n1 + 16) * 20 + (c4 << 2)];
        const float4 xc = (c4 == 0) ? x0 : (c4 == 1) ? x1 : (c4 == 2) ? x2 : x3;
        t1 += A1.x * xc.x + A1.y * xc.y + A1.z * xc.z + A1.w * xc.w;
        t2 += A2.x * xc.x + A2.y * xc.y + A2.z * xc.z + A2.w * xc.w;
      }
      const float l1a = t1 * 0.03125f, l1b = t2 * 0.03125f;   // b1 = t/32
      const float e1a = exp2f(l1a * LOG2E), e1b = exp2f(l1b * LOG2E);
      float s1 = e1a + e1b;
      s1 = dpp_addf<DPP_XOR1>(s1); s1 = dpp_addf<DPP_XOR2>(s1);
      s1 = dpp_addf<DPP_HALF_MIR>(s1); s1 = dpp_addf<DPP_ROW_MIR>(s1);
      const float rs1 = __builtin_amdgcn_rcpf(s1);
      const float l2a = l1a + e1a * rs1 * t1;                 // b2 = b1 + c1*t
      const float l2b = l1b + e1b * rs1 * t2;
      const float e2a = exp2f(l2a * LOG2E), e2b = exp2f(l2b * LOG2E);
      float s2 = e2a + e2b;
      s2 = dpp_addf<DPP_XOR1>(s2); s2 = dpp_addf<DPP_XOR2>(s2);
      s2 = dpp_addf<DPP_HALF_MIR>(s2); s2 = dpp_addf<DPP_ROW_MIR>(s2);
      const float rs2 = __builtin_amdgcn_rcpf(s2);
      sC[n1 * 36 + bB]        = e2a * rs2;
      sC[(n1 + 16) * 36 + bB] = e2b * rs2;
    }
    lds_barrier();                            // sC ready (vmcnt untouched)

    // ---- pass 2: x in SGPRs (s_load), FMAs v*s -> acc ----
    float c2s[16];
    {
      const int cb = nr * 36 + (bh << 4);
      *(float4*)&c2s[0]  = *(const float4*)&sC[cb + 0];
      *(float4*)&c2s[4]  = *(const float4*)&sC[cb + 4];
      *(float4*)&c2s[8]  = *(const float4*)&sC[cb + 8];
      *(float4*)&c2s[12] = *(const float4*)&sC[cb + 12];
    }
    const size_t xoff = ((size_t)(i0 + ii) << 4);
    const float* pbase = uniform_fptr(X + (((size_t)(bh << 4)) << 15) + xoff);
    #pragma unroll
    for (int cl = 0; cl < 8; ++cl) {
      const float* p0 = pbase + ((size_t)(cl << 1) << 15);  // SGPR arithmetic
      const float* p1 = p0 + 32768;
      f4v xa0, xa1, xa2, xa3, xb0, xb1, xb2, xb3;
      sload_x2(p0, p1, xa0, xa1, xa2, xa3, xb0, xb1, xb2, xb3);
      float u0 = wa0.x*xa0.x + wa0.y*xa0.y + wa0.z*xa0.z + wa0.w*xa0.w
               + wa1.x*xa1.x + wa1.y*xa1.y + wa1.z*xa1.z + wa1.w*xa1.w
               + wa2.x*xa2.x + wa2.y*xa2.y + wa2.z*xa2.z + wa2.w*xa2.w
               + wa3.x*xa3.x + wa3.y*xa3.y + wa3.z*xa3.z + wa3.w*xa3.w;
      float u1 = wb0.x*xa0.x + wb0.y*xa0.y + wb0.z*xa0.z + wb0.w*xa0.w
               + wb1.x*xa1.x + wb1.y*xa1.y + wb1.z*xa1.z + wb1.w*xa1.w
               + wb2.x*xa2.x + wb2.y*xa2.y + wb2.z*xa2.z + wb2.w*xa2.w
               + wb3.x*xa3.x + wb3.y*xa3.y + wb3.z*xa3.z + wb3.w*xa3.w;
      float v0 = wa0.x*xb0.x + wa0.y*xb0.y + wa0.z*xb0.z + wa0.w*xb0.w
               + wa1.x*xb1.x + wa1.y*xb1.y + wa1.z*xb1.z + wa1.w*xb1.w
               + wa2.x*xb2.x + wa2.y*xb2.y + wa2.z*xb2.z + wa2.w*xb2.w
               + wa3.x*xb3.x + wa3.y*xb3.y + wa3.z*xb3.z + wa3.w*xb3.w;
      float v1 = wb0.x*xb0.x + wb0.y*xb0.y + wb0.z*xb0.z + wb0.w*xb0.w
               + wb1.x*xb1.x + wb1.y*xb1.y + wb1.z*xb1.z + wb1.w*xb1.w
               + wb2.x*xb2.x + wb2.y*xb2.y + wb2.z*xb2.z + wb2.w*xb2.w
               + wb3.x*xb3.x + wb3.y*xb3.y + wb3.z*xb3.z + wb3.w*xb3.w;
      acc0[(cl << 1)    ] += c2s[(cl << 1)    ] * u0;
      acc1[(cl << 1)    ] += c2s[(cl << 1)    ] * u1;
      acc0[(cl << 1) + 1] += c2s[(cl << 1) + 1] * v0;
      acc1[(cl << 1) + 1] += c2s[(cl << 1) + 1] * v1;
    }
  }

  if constexpr (ATOMIC) {
    #pragma unroll
    for (int j = 0; j < 16; ++j) {
      const int bgl = (bh << 4) + j;
      float* dst = part + ((size_t)bgl << 9) + (t256 << 1);
      atomicAdd(dst, acc0[j]);
      atomicAdd(dst + 1, acc1[j]);
    }
  } else {
    float* wp = part + ((size_t)blockIdx.x << 14) + (t256 << 1);
    #pragma unroll
    for (int j = 0; j < 16; ++j) {
      const int bgl = (bh << 4) + j;
      *(float2*)(wp + ((size_t)bgl << 9)) = make_float2(acc0[j], acc1[j]);
    }
  }
}

// K2: reduce 512 partials + squash. grid 256 (b = bid>>3, r-block = bid&7).
__global__ __launch_bounds__(512)
void caps_reduce(const float* __restrict__ part, float* __restrict__ out) {
  __shared__ float sred[32][64];
  const int tid = threadIdx.x;
  const int bid = blockIdx.x;            // 0..255
  const int b  = bid >> 3;               // 0..31
  const int rb = bid & 7;                // 64-elem row block
  const int pg = tid >> 4;               // 0..31: sums ig in [16pg, 16pg+16)
  const int sl = tid & 15;               // float4 slot
  const float* src = part + (((size_t)pg << 4) << 14)
                   + (b << 9) + (rb << 6) + (sl << 2);
  float4 a = make_float4(0.f, 0.f, 0.f, 0.f);
  #pragma unroll 4
  for (int p = 0; p < 16; ++p) {
    const float4 v = *(const float4*)(src + ((size_t)p << 14));
    a.x += v.x; a.y += v.y; a.z += v.z; a.w += v.w;
  }
  *(float4*)&sred[pg][sl << 2] = a;
  __syncthreads();
  if (tid < 64) {
    float s = 0.f;
    #pragma unroll
    for (int g = 0; g < 32; ++g) s += sred[g][tid];
    float sq = s * s;
    sq += __shfl_xor(sq, 1); sq += __shfl_xor(sq, 2);
    sq += __shfl_xor(sq, 4); sq += __shfl_xor(sq, 8);   // sum over d (16 r's)
    const float scale = sq / (1.0f + sq) / sqrtf(sq + 1e-7f);
    out[(b << 9) + (rb << 6) + tid] = scale * s;
  }
}

// fallback path: squash fully-accumulated sums
__global__ __launch_bounds__(256)
void caps_squash(const float* __restrict__ sums, float* __restrict__ out) {
  const int e = (blockIdx.x << 8) + threadIdx.x;
  const float s = sums[e];
  float sq = s * s;
  sq += __shfl_xor(sq, 1); sq += __shfl_xor(sq, 2);
  sq += __shfl_xor(sq, 4); sq += __shfl_xor(sq, 8);
  const float scale = sq / (1.0f + sq) / sqrtf(sq + 1e-7f);
  out[e] = scale * s;
}

extern "C" void kernel_launch(void* const* d_in, const int* in_sizes, int n_in,
                              void* d_out, int out_size, void* d_ws, size_t ws_size,
                              hipStream_t stream) {
  const float* X  = (const float*)d_in[0];
  const float* Wt = (const float*)d_in[1];
  float* out = (float*)d_out;
  float* wsf = (float*)d_ws;
  const size_t need = (size_t)512 * 16384 * sizeof(float);
  if (ws_size >= need) {
    caps_main<false><<<512, 512, 0, stream>>>(X, Wt, wsf);
    caps_reduce<<<256, 512, 0, stream>>>(wsf, out);
  } else {
    float* acc = (ws_size >= (size_t)16384 * sizeof(float)) ? wsf : out;
    hipMemsetAsync(acc, 0, 16384 * sizeof(float), stream);
    caps_main<true><<<512, 512, 0, stream>>>(X, Wt, acc);
    caps_squash<<<64, 256, 0, stream>>>(acc, out);
  }
}

// Round 8
// 44.464 us; speedup vs baseline: 2.6532x; 1.0300x over previous
//
#include <hip/hip_runtime.h>
#include <cstdint>
#include <cstddef>

#define LOG2E 1.4426950408889634f

// ---- DPP cross-lane add: v += v[permuted lane] (pure VALU, no LDS pipe) ----
template<int CTRL>
__device__ __forceinline__ float dpp_addf(float v) {
  const int s = __builtin_amdgcn_update_dpp(
      0, __builtin_bit_cast(int, v), CTRL, 0xF, 0xF, true);
  return v + __builtin_bit_cast(float, s);
}
#define DPP_XOR1     0xB1   // quad_perm [1,0,3,2]
#define DPP_XOR2     0x4E   // quad_perm [2,3,0,1]
#define DPP_HALF_MIR 0x141  // 8-lane mirror (completes 8-group after XOR1,2)
#define DPP_ROW_MIR  0x140  // 16-lane mirror (completes 16-group)

// async global->LDS: HW writes wave-uniform LDS base + lane*16B (vmcnt)
__device__ __forceinline__ void gld_lds16(const float* g, float* l) {
  __builtin_amdgcn_global_load_lds(
      (const __attribute__((address_space(1))) void*)g,
      (__attribute__((address_space(3))) void*)l, 16, 0, 0);
}

// involution swizzle on 16B-block index: frag reads land 8 lanes/bank-quad
__device__ __forceinline__ int swz(int b) { return b ^ ((b >> 3) & 7); }

// stage one 16KB half (512 rows x 8 k), 8-wave block: LDS[blk]=G[swz(blk)]
__device__ __forceinline__ void stage_half(const float* Wg, float* buf,
                                           int wv, int ln) {
  #pragma unroll
  for (int t = 0; t < 2; ++t) {
    const int seg = ((wv << 1) + t) << 8;      // wave-uniform dest word base
    const int j   = swz((seg >> 2) + ln);      // source 16B-block for this slot
    gld_lds16(Wg + ((j >> 1) << 4) + ((j & 1) << 2), buf + seg);
  }
}

// full 32KB W tile for one i: k 0..7 -> buf[0..4095], k 8..15 -> buf[4096..]
__device__ __forceinline__ void stage_tile(const float* WtI, float* buf,
                                           int wv, int ln) {
  stage_half(WtI,     buf,        wv, ln);
  stage_half(WtI + 8, buf + 4096, wv, ln);
}

// x[b][0..15] for one i, all 32 b -> 512 words LDS linear [b][k]; waves 0-1.
__device__ __forceinline__ void stage_x(const float* Xi, float* dst, int tid) {
  if (tid < 128) {
    gld_lds16(Xi + ((size_t)(tid >> 2) << 15) + ((tid & 3) << 2),
              dst + ((tid >> 6) << 8));
  }
}

// barrier waiting LDS ops only; async staging (vmcnt) stays in flight (T4)
__device__ __forceinline__ void lds_barrier() {
  asm volatile("s_waitcnt lgkmcnt(0)\n\ts_barrier" ::: "memory");
}

// K1: grid 512 (bg=1: W read once), block 512 thr (8 waves), 4 i's x all 32 b.
//
// Round-7 established: ROLLED loop (no buffer parity in compile-time form)
// is what keeps allocation at ~72-110 VGPR; the 4x unroll was the spill
// poison of rounds 1-6. Round 8 keeps the rolled single-sW deep-prefetch
// structure and moves ALL x consumption to LDS:
//   - sX[2][512] double buffer, runtime parity p=ii&1 (address math only --
//     legal in a rolled loop; the compiler inserts NO automatic vmcnt waits
//     for global_load_lds->ds_read hazards, so ordering comes from the
//     loop-top __syncthreads drain at FULL-ITERATION prefetch distance).
//   - phase B reads x from sX[p] (broadcast ds_read, no vmem wait at all;
//     replaces 4 per-lane global float4 loads + their latency).
//   - pass 2 reads x via wave-uniform ds_read_b128 from sX[p]. DS returns
//     IN-ORDER, so the compiler pipelines all reads against the FMAs with
//     counted lgkmcnt -- replacing 8 serialized s_load chains whose
//     lgkmcnt(0) waits (SMEM is out-of-order: counted waits illegal) each
//     exposed ~200-400 cyc of scalar-cache miss latency in wave lockstep.
template<bool ATOMIC>
__global__ __launch_bounds__(512)
void caps_main(const float* __restrict__ X, const float* __restrict__ Wt,
               float* __restrict__ part) {
  __shared__ float sW[8192];        // 32 KB: single W tile (deep prefetch)
  __shared__ float sX[2][512];      // 4 KB: double-buffered x tiles
  __shared__ float sWs[32 * 20];    // d-summed W (2.5 KB)
  __shared__ float sC[32 * 36];     // c2[n][b] (4.5 KB)
  __shared__ float sPad[2688];      // shaper: total 53.5KB -> 2 blk/CU
  if ((int)blockIdx.x == -1) sPad[threadIdx.x] = 1.f;   // keep sPad allocated

  const int tid  = threadIdx.x;
  const int wv   = tid >> 6, ln = tid & 63;
  const int t256 = tid & 255;
  const int bh   = tid >> 8;                  // b-half for pass 2
  const int i0   = blockIdx.x << 2;

  stage_tile(Wt + ((size_t)i0 << 13), sW, wv, ln);
  stage_x(X + ((size_t)i0 << 4), sX[0], tid);

  const int bB = tid >> 4;                    // phase-B batch 0..31
  const int n1 = tid & 15;                    // phase-B n-low
  const int j0 = t256 << 2;                   // lane's base 16B-block
  const int nr = t256 >> 3;                   // lane's capsule (both rows)

  float acc0[16], acc1[16];
  #pragma unroll
  for (int b = 0; b < 16; ++b) { acc0[b] = 0.f; acc1[b] = 0.f; }

  #pragma clang loop unroll(disable)
  for (int ii = 0; ii < 4; ++ii) {
    const int p = ii & 1;           // runtime parity: address math only
    __syncthreads();                // vmcnt drain: W(ii)+x(ii) staged full
                                    // iteration ago -> wait is ~free

    // ---- phase A: all 8 lane rows -> regs (tile ii) ----
    const float4 wa0 = *(const float4*)&sW[swz(j0 + 0) << 2];
    const float4 wa1 = *(const float4*)&sW[swz(j0 + 1) << 2];
    const float4 wb0 = *(const float4*)&sW[swz(j0 + 2) << 2];
    const float4 wb1 = *(const float4*)&sW[swz(j0 + 3) << 2];
    const float4 wa2 = *(const float4*)&sW[4096 + (swz(j0 + 0) << 2)];
    const float4 wa3 = *(const float4*)&sW[4096 + (swz(j0 + 1) << 2)];
    const float4 wb2 = *(const float4*)&sW[4096 + (swz(j0 + 2) << 2)];
    const float4 wb3 = *(const float4*)&sW[4096 + (swz(j0 + 3) << 2)];

    lds_barrier();                  // all waves' frag reads done; sW free
                                    // (lgkm-only: vmcnt stays in flight)

    if (ii < 3) {                   // stage next i: full-iteration distance
      stage_x(X + ((size_t)(i0 + ii + 1) << 4), sX[p ^ 1], tid);
      stage_tile(Wt + ((size_t)(i0 + ii + 1) << 13), sW, wv, ln);
    }                               // async; drained at next loop-top sync

    // ---- Ws[n][k] from frags via DPP 8-lane reduce (waves 0-3 cover all n) ----
    if (tid < 256) {
      float pr[16] = { wa0.x+wb0.x, wa0.y+wb0.y, wa0.z+wb0.z, wa0.w+wb0.w,
                       wa1.x+wb1.x, wa1.y+wb1.y, wa1.z+wb1.z, wa1.w+wb1.w,
                       wa2.x+wb2.x, wa2.y+wb2.y, wa2.z+wb2.z, wa2.w+wb2.w,
                       wa3.x+wb3.x, wa3.y+wb3.y, wa3.z+wb3.z, wa3.w+wb3.w };
      #pragma unroll
      for (int q = 0; q < 16; ++q) {
        float v = pr[q];
        v = dpp_addf<DPP_XOR1>(v);
        v = dpp_addf<DPP_XOR2>(v);
        v = dpp_addf<DPP_HALF_MIR>(v);
        pr[q] = v;
      }
      if ((tid & 7) < 4) {
        const int m = tid & 3;
        const float4 w =
            (m & 2) ? ((m & 1) ? make_float4(pr[12], pr[13], pr[14], pr[15])
                               : make_float4(pr[8],  pr[9],  pr[10], pr[11]))
                    : ((m & 1) ? make_float4(pr[4],  pr[5],  pr[6],  pr[7])
                               : make_float4(pr[0],  pr[1],  pr[2],  pr[3]));
        *(float4*)&sWs[(t256 >> 3) * 20 + (m << 2)] = w;
      }
    }
    lds_barrier();                            // sWs ready (vmcnt untouched)

    // ---- phase B: x from LDS (broadcast) -> 2-round softmax -> sC ----
    {
      const float* xr = &sX[p][bB << 4];
      const float4 x0 = *(const float4*)(xr + 0);
      const float4 x1 = *(const float4*)(xr + 4);
      const float4 x2 = *(const float4*)(xr + 8);
      const float4 x3 = *(const float4*)(xr + 12);
      float t1 = 0.f, t2 = 0.f;
      #pragma unroll
      for (int c4 = 0; c4 < 4; ++c4) {
        const float4 A1 = *(const float4*)&sWs[n1 * 20 + (c4 << 2)];
        const float4 A2 = *(const float4*)&sWs[(n1 + 16) * 20 + (c4 << 2)];
        const float4 xc = (c4 == 0) ? x0 : (c4 == 1) ? x1 : (c4 == 2) ? x2 : x3;
        t1 += A1.x * xc.x + A1.y * xc.y + A1.z * xc.z + A1.w * xc.w;
        t2 += A2.x * xc.x + A2.y * xc.y + A2.z * xc.z + A2.w * xc.w;
      }
      const float l1a = t1 * 0.03125f, l1b = t2 * 0.03125f;   // b1 = t/32
      const float e1a = exp2f(l1a * LOG2E), e1b = exp2f(l1b * LOG2E);
      float s1 = e1a + e1b;
      s1 = dpp_addf<DPP_XOR1>(s1); s1 = dpp_addf<DPP_XOR2>(s1);
      s1 = dpp_addf<DPP_HALF_MIR>(s1); s1 = dpp_addf<DPP_ROW_MIR>(s1);
      const float rs1 = __builtin_amdgcn_rcpf(s1);
      const float l2a = l1a + e1a * rs1 * t1;                 // b2 = b1 + c1*t
      const float l2b = l1b + e1b * rs1 * t2;
      const float e2a = exp2f(l2a * LOG2E), e2b = exp2f(l2b * LOG2E);
      float s2 = e2a + e2b;
      s2 = dpp_addf<DPP_XOR1>(s2); s2 = dpp_addf<DPP_XOR2>(s2);
      s2 = dpp_addf<DPP_HALF_MIR>(s2); s2 = dpp_addf<DPP_ROW_MIR>(s2);
      const float rs2 = __builtin_amdgcn_rcpf(s2);
      sC[n1 * 36 + bB]        = e2a * rs2;
      sC[(n1 + 16) * 36 + bB] = e2b * rs2;
    }
    lds_barrier();                            // sC ready (vmcnt untouched)

    // ---- pass 2: x via wave-uniform ds_read_b128 (in-order DS returns ->
    // compiler pipelines reads against FMAs with counted lgkmcnt) ----
    float c2s[16];
    {
      const int cb = nr * 36 + (bh << 4);
      *(float4*)&c2s[0]  = *(const float4*)&sC[cb + 0];
      *(float4*)&c2s[4]  = *(const float4*)&sC[cb + 4];
      *(float4*)&c2s[8]  = *(const float4*)&sC[cb + 8];
      *(float4*)&c2s[12] = *(const float4*)&sC[cb + 12];
    }
    const float* xp0 = &sX[p][bh << 8];       // this wave's 16-b half
    #pragma unroll
    for (int st = 0; st < 16; ++st) {
      const float* xp = xp0 + (st << 4);      // b = bh*16 + st (wave-uniform)
      const float4 xa0 = *(const float4*)(xp + 0);
      const float4 xa1 = *(const float4*)(xp + 4);
      const float4 xa2 = *(const float4*)(xp + 8);
      const float4 xa3 = *(const float4*)(xp + 12);
      float u0 = wa0.x*xa0.x + wa0.y*xa0.y + wa0.z*xa0.z + wa0.w*xa0.w
               + wa1.x*xa1.x + wa1.y*xa1.y + wa1.z*xa1.z + wa1.w*xa1.w
               + wa2.x*xa2.x + wa2.y*xa2.y + wa2.z*xa2.z + wa2.w*xa2.w
               + wa3.x*xa3.x + wa3.y*xa3.y + wa3.z*xa3.z + wa3.w*xa3.w;
      float u1 = wb0.x*xa0.x + wb0.y*xa0.y + wb0.z*xa0.z + wb0.w*xa0.w
               + wb1.x*xa1.x + wb1.y*xa1.y + wb1.z*xa1.z + wb1.w*xa1.w
               + wb2.x*xa2.x + wb2.y*xa2.y + wb2.z*xa2.z + wb2.w*xa2.w
               + wb3.x*xa3.x + wb3.y*xa3.y + wb3.z*xa3.z + wb3.w*xa3.w;
      acc0[st] += c2s[st] * u0;
      acc1[st] += c2s[st] * u1;
    }
  }

  if constexpr (ATOMIC) {
    #pragma unroll
    for (int j = 0; j < 16; ++j) {
      const int bgl = (bh << 4) + j;
      float* dst = part + ((size_t)bgl << 9) + (t256 << 1);
      atomicAdd(dst, acc0[j]);
      atomicAdd(dst + 1, acc1[j]);
    }
  } else {
    float* wp = part + ((size_t)blockIdx.x << 14) + (t256 << 1);
    #pragma unroll
    for (int j = 0; j < 16; ++j) {
      const int bgl = (bh << 4) + j;
      *(float2*)(wp + ((size_t)bgl << 9)) = make_float2(acc0[j], acc1[j]);
    }
  }
}

// K2: reduce 512 partials + squash. grid 256 (b = bid>>3, r-block = bid&7).
__global__ __launch_bounds__(512)
void caps_reduce(const float* __restrict__ part, float* __restrict__ out) {
  __shared__ float sred[32][64];
  const int tid = threadIdx.x;
  const int bid = blockIdx.x;            // 0..255
  const int b  = bid >> 3;               // 0..31
  const int rb = bid & 7;                // 64-elem row block
  const int pg = tid >> 4;               // 0..31: sums ig in [16pg, 16pg+16)
  const int sl = tid & 15;               // float4 slot
  const float* src = part + (((size_t)pg << 4) << 14)
                   + (b << 9) + (rb << 6) + (sl << 2);
  float4 a = make_float4(0.f, 0.f, 0.f, 0.f);
  #pragma unroll 4
  for (int p = 0; p < 16; ++p) {
    const float4 v = *(const float4*)(src + ((size_t)p << 14));
    a.x += v.x; a.y += v.y; a.z += v.z; a.w += v.w;
  }
  *(float4*)&sred[pg][sl << 2] = a;
  __syncthreads();
  if (tid < 64) {
    float s = 0.f;
    #pragma unroll
    for (int g = 0; g < 32; ++g) s += sred[g][tid];
    float sq = s * s;
    sq += __shfl_xor(sq, 1); sq += __shfl_xor(sq, 2);
    sq += __shfl_xor(sq, 4); sq += __shfl_xor(sq, 8);   // sum over d (16 r's)
    const float scale = sq / (1.0f + sq) / sqrtf(sq + 1e-7f);
    out[(b << 9) + (rb << 6) + tid] = scale * s;
  }
}

// fallback path: squash fully-accumulated sums
__global__ __launch_bounds__(256)
void caps_squash(const float* __restrict__ sums, float* __restrict__ out) {
  const int e = (blockIdx.x << 8) + threadIdx.x;
  const float s = sums[e];
  float sq = s * s;
  sq += __shfl_xor(sq, 1); sq += __shfl_xor(sq, 2);
  sq += __shfl_xor(sq, 4); sq += __shfl_xor(sq, 8);
  const float scale = sq / (1.0f + sq) / sqrtf(sq + 1e-7f);
  out[e] = scale * s;
}

extern "C" void kernel_launch(void* const* d_in, const int* in_sizes, int n_in,
                              void* d_out, int out_size, void* d_ws, size_t ws_size,
                              hipStream_t stream) {
  const float* X  = (const float*)d_in[0];
  const float* Wt = (const float*)d_in[1];
  float* out = (float*)d_out;
  float* wsf = (float*)d_ws;
  const size_t need = (size_t)512 * 16384 * sizeof(float);
  if (ws_size >= need) {
    caps_main<false><<<512, 512, 0, stream>>>(X, Wt, wsf);
    caps_reduce<<<256, 512, 0, stream>>>(wsf, out);
  } else {
    float* acc = (ws_size >= (size_t)16384 * sizeof(float)) ? wsf : out;
    hipMemsetAsync(acc, 0, 16384 * sizeof(float), stream);
    caps_main<true><<<512, 512, 0, stream>>>(X, Wt, acc);
    caps_squash<<<64, 256, 0, stream>>>(acc, out);
  }
}